// Round 14
// baseline (255.842 us; speedup 1.0000x reference)
//
#include <hip/hip_runtime.h>

#define NPTS   16384
#define RPB    256      // rows per block (4 waves x 64)
#define CPB    512      // cols per block
#define NRB    (NPTS / RPB)   // 64
#define NCB    (NPTS / CPB)   // 32

typedef short  bf16x8 __attribute__((ext_vector_type(8)));
typedef float  f32x16 __attribute__((ext_vector_type(16)));

__device__ __forceinline__ unsigned rne_bf16(float f) {
    unsigned u = __float_as_uint(f);
    return (u + 0x7fffu + ((u >> 16) & 1u)) >> 16;
}
__device__ __forceinline__ float bf16_dec(unsigned h) {
    return __uint_as_float(h << 16);
}
#define ONE_BF 0x3f80u

__device__ __forceinline__ float tree16_min(f32x16 a) {
    float x0 = fminf(fminf(a[0],  a[1]),  a[2]);
    float x1 = fminf(fminf(a[3],  a[4]),  a[5]);
    float x2 = fminf(fminf(a[6],  a[7]),  a[8]);
    float x3 = fminf(fminf(a[9],  a[10]), a[11]);
    float x4 = fminf(fminf(a[12], a[13]), a[14]);
    float y0 = fminf(fminf(x0, x1), x2);
    float y1 = fminf(fminf(x3, x4), a[15]);
    return fminf(y0, y1);
}

__global__ __launch_bounds__(256) void prep_kernel(
    const float4* __restrict__ pred, const float4* __restrict__ tgt,
    uint4* __restrict__ wpred, uint4* __restrict__ ptgt,
    unsigned int* __restrict__ minbuf)
{
    int i = blockIdx.x * 256 + threadIdx.x;
    if (i >= NPTS) return;
    minbuf[i]        = 0x7f7f7f7fu;
    minbuf[i + NPTS] = 0x7f7f7f7fu;
    unsigned onepk = ONE_BF | (ONE_BF << 16);
    {
        float4 v = pred[i];
        float n = fmaf(v.x, v.x, fmaf(v.y, v.y, fmaf(v.z, v.z, 0.5f * v.w * v.w)));
        unsigned nh = rne_bf16(n);
        unsigned nl = rne_bf16(n - bf16_dec(nh));
        unsigned npk = nh | (nl << 16);
        float w0 = -2.0f * v.x, w1 = -2.0f * v.y, w2 = -2.0f * v.z, w3 = -v.w;
        unsigned h0 = rne_bf16(w0), h1 = rne_bf16(w1), h2 = rne_bf16(w2), h3 = rne_bf16(w3);
        unsigned l0 = rne_bf16(w0 - bf16_dec(h0)), l1 = rne_bf16(w1 - bf16_dec(h1));
        unsigned l2 = rne_bf16(w2 - bf16_dec(h2)), l3 = rne_bf16(w3 - bf16_dec(h3));
        wpred[i * 2 + 0] = make_uint4(h0 | (h1 << 16), h2 | (h3 << 16),
                                      l0 | (l1 << 16), l2 | (l3 << 16));
        wpred[i * 2 + 1] = make_uint4(h0 | (h1 << 16), h2 | (h3 << 16), onepk, npk);
    }
    {
        float4 v = tgt[i];
        float n = fmaf(v.x, v.x, fmaf(v.y, v.y, fmaf(v.z, v.z, 0.5f * v.w * v.w)));
        unsigned nh = rne_bf16(n);
        unsigned nl = rne_bf16(n - bf16_dec(nh));
        unsigned npk = nh | (nl << 16);
        unsigned g0 = rne_bf16(v.x), g1 = rne_bf16(v.y), g2 = rne_bf16(v.z), g3 = rne_bf16(v.w);
        unsigned m0 = rne_bf16(v.x - bf16_dec(g0)), m1 = rne_bf16(v.y - bf16_dec(g1));
        unsigned m2 = rne_bf16(v.z - bf16_dec(g2)), m3 = rne_bf16(v.w - bf16_dec(g3));
        ptgt[i * 2 + 0] = make_uint4(g0 | (g1 << 16), g2 | (g3 << 16),
                                     g0 | (g1 << 16), g2 | (g3 << 16));
        ptgt[i * 2 + 1] = make_uint4(m0 | (m1 << 16), m2 | (m3 << 16), npk, onepk);
    }
}

// ---------------- ablation probe (MEASUREMENT ONLY, writes scratch) --------
// V0 full R12 loop; V1 rows-only; V2 rows no-epilogue; V3 mfma+loads; V4 loads.
template<int V>
__global__ __launch_bounds__(256, 4) void probe_kernel(
    const bf16x8* __restrict__ wpred, const bf16x8* __restrict__ ptgt,
    float* __restrict__ srow, float* __restrict__ scol)
{
    __shared__ unsigned colLds[CPB];
    __shared__ float red[RPB];
    if constexpr (V == 0) {
        for (int c = threadIdx.x; c < CPB; c += 256) colLds[c] = 0x7f7f7f7fu;
        __syncthreads();
    }
    const int lane = threadIdx.x & 63;
    const int wave = threadIdx.x >> 6;
    const int half = lane >> 5;
    const int lid  = lane & 31;
    const int rowBase = blockIdx.x * RPB + wave * 64;
    const int colBase = blockIdx.y * CPB;

    bf16x8 a0 = wpred[(rowBase +      lid) * 2 + half];
    bf16x8 a1 = wpred[(rowBase + 32 + lid) * 2 + half];

    float mr0[16], mr1[16];
#pragma unroll
    for (int r = 0; r < 16; ++r) { mr0[r] = 3.0e38f; mr1[r] = 3.0e38f; }
    float msink = 3.0e38f;
    int   isink = 0;

    const bf16x8* bp = ptgt + (colBase + lid) * 2 + half;
    const f32x16 kZero = (f32x16)(0.0f);

#pragma unroll 2
    for (int t = 0; t < CPB / 64; ++t) {
        bf16x8 b0 = bp[t * 128];
        bf16x8 b1 = bp[t * 128 + 64];
        if constexpr (V == 4) {
            isink ^= (int)b0[0] ^ (int)b0[7] ^ (int)b1[0] ^ (int)b1[7];
        } else {
            f32x16 A0 = __builtin_amdgcn_mfma_f32_32x32x16_bf16(a0, b0, kZero, 0, 0, 0);
            f32x16 A1 = __builtin_amdgcn_mfma_f32_32x32x16_bf16(a0, b1, kZero, 0, 0, 0);
            if constexpr (V <= 2) {
#pragma unroll
                for (int r = 0; r < 16; ++r)
                    mr0[r] = fminf(fminf(A0[r], A1[r]), mr0[r]);
            } else {
                msink = fminf(fminf(A0[0], A1[0]), msink);
            }
            float ta = 0.0f, tb = 0.0f;
            if constexpr (V == 0) { ta = tree16_min(A0); tb = tree16_min(A1); }
            __builtin_amdgcn_sched_barrier(0x20);
            f32x16 B0 = __builtin_amdgcn_mfma_f32_32x32x16_bf16(a1, b0, kZero, 0, 0, 0);
            f32x16 B1 = __builtin_amdgcn_mfma_f32_32x32x16_bf16(a1, b1, kZero, 0, 0, 0);
            if constexpr (V <= 2) {
#pragma unroll
                for (int r = 0; r < 16; ++r)
                    mr1[r] = fminf(fminf(B0[r], B1[r]), mr1[r]);
            } else {
                msink = fminf(fminf(B0[0], B1[0]), msink);
            }
            if constexpr (V == 0) {
                ta = fminf(ta, tree16_min(B0));
                tb = fminf(tb, tree16_min(B1));
                atomicMin(&colLds[t * 64 +      lid], __float_as_uint(fmaxf(ta, 0.0f)));
                atomicMin(&colLds[t * 64 + 32 + lid], __float_as_uint(fmaxf(tb, 0.0f)));
            }
            __builtin_amdgcn_sched_barrier(0x20);
        }
    }

    if constexpr (V >= 3) {
        asm volatile("" :: "v"(msink), "v"(isink));
        return;
    }
    if constexpr (V == 2) {
        float s = 3.0e38f;
#pragma unroll
        for (int r = 0; r < 16; ++r) s = fminf(fminf(mr0[r], mr1[r]), s);
        asm volatile("" :: "v"(s));
        return;
    }
    // V0 / V1: full row epilogue + stores to distinct scratch slots
#pragma unroll
    for (int r = 0; r < 16; ++r) {
        float v0 = mr0[r], v1 = mr1[r];
        v0 = fminf(v0, __shfl_xor(v0, 16)); v1 = fminf(v1, __shfl_xor(v1, 16));
        v0 = fminf(v0, __shfl_xor(v0, 8));  v1 = fminf(v1, __shfl_xor(v1, 8));
        v0 = fminf(v0, __shfl_xor(v0, 4));  v1 = fminf(v1, __shfl_xor(v1, 4));
        v0 = fminf(v0, __shfl_xor(v0, 2));  v1 = fminf(v1, __shfl_xor(v1, 2));
        v0 = fminf(v0, __shfl_xor(v0, 1));  v1 = fminf(v1, __shfl_xor(v1, 1));
        if (lid == 0) {
            int row = (r & 3) + 8 * (r >> 2) + 4 * half;
            red[wave * 64 + row]      = v0;
            red[wave * 64 + 32 + row] = v1;
        }
    }
    __syncthreads();
    srow[((size_t)blockIdx.z * NCB + blockIdx.y) * NPTS + blockIdx.x * RPB + threadIdx.x]
        = fmaxf(red[threadIdx.x], 0.0f);
    if constexpr (V == 0) {
#pragma unroll
        for (int s = 0; s < 2; ++s) {
            int c = threadIdx.x + s * 256;
            scol[((size_t)blockIdx.z * NRB + blockIdx.x) * NPTS + colBase + c]
                = __uint_as_float(colLds[c]);
        }
    }
}

// ---------------- real chain (R12, proven 36.1us) --------------------------
__global__ __launch_bounds__(256, 4) void chamfer_mfma_kernel(
    const bf16x8* __restrict__ wpred, const bf16x8* __restrict__ ptgt,
    unsigned int* __restrict__ minbuf)
{
    __shared__ unsigned colLds[CPB];
    __shared__ float red[RPB];
    for (int c = threadIdx.x; c < CPB; c += 256) colLds[c] = 0x7f7f7f7fu;
    __syncthreads();

    const int lane = threadIdx.x & 63;
    const int wave = threadIdx.x >> 6;
    const int half = lane >> 5;
    const int lid  = lane & 31;
    const int rowBase = blockIdx.x * RPB + wave * 64;
    const int colBase = blockIdx.y * CPB;

    bf16x8 a0 = wpred[(rowBase +      lid) * 2 + half];
    bf16x8 a1 = wpred[(rowBase + 32 + lid) * 2 + half];

    float mr0[16], mr1[16];
#pragma unroll
    for (int r = 0; r < 16; ++r) { mr0[r] = 3.0e38f; mr1[r] = 3.0e38f; }

    const bf16x8* bp = ptgt + (colBase + lid) * 2 + half;
    const f32x16 kZero = (f32x16)(0.0f);

#pragma unroll 2
    for (int t = 0; t < CPB / 64; ++t) {
        bf16x8 b0 = bp[t * 128];
        bf16x8 b1 = bp[t * 128 + 64];
        f32x16 A0 = __builtin_amdgcn_mfma_f32_32x32x16_bf16(a0, b0, kZero, 0, 0, 0);
        f32x16 A1 = __builtin_amdgcn_mfma_f32_32x32x16_bf16(a0, b1, kZero, 0, 0, 0);
#pragma unroll
        for (int r = 0; r < 16; ++r)
            mr0[r] = fminf(fminf(A0[r], A1[r]), mr0[r]);
        float ta = tree16_min(A0);
        float tb = tree16_min(A1);
        __builtin_amdgcn_sched_barrier(0x20);
        f32x16 B0 = __builtin_amdgcn_mfma_f32_32x32x16_bf16(a1, b0, kZero, 0, 0, 0);
        f32x16 B1 = __builtin_amdgcn_mfma_f32_32x32x16_bf16(a1, b1, kZero, 0, 0, 0);
#pragma unroll
        for (int r = 0; r < 16; ++r)
            mr1[r] = fminf(fminf(B0[r], B1[r]), mr1[r]);
        ta = fminf(ta, tree16_min(B0));
        tb = fminf(tb, tree16_min(B1));
        __builtin_amdgcn_sched_barrier(0x20);
        atomicMin(&colLds[t * 64 +      lid], __float_as_uint(fmaxf(ta, 0.0f)));
        atomicMin(&colLds[t * 64 + 32 + lid], __float_as_uint(fmaxf(tb, 0.0f)));
    }

#pragma unroll
    for (int r = 0; r < 16; ++r) {
        float v0 = mr0[r], v1 = mr1[r];
        v0 = fminf(v0, __shfl_xor(v0, 16)); v1 = fminf(v1, __shfl_xor(v1, 16));
        v0 = fminf(v0, __shfl_xor(v0, 8));  v1 = fminf(v1, __shfl_xor(v1, 8));
        v0 = fminf(v0, __shfl_xor(v0, 4));  v1 = fminf(v1, __shfl_xor(v1, 4));
        v0 = fminf(v0, __shfl_xor(v0, 2));  v1 = fminf(v1, __shfl_xor(v1, 2));
        v0 = fminf(v0, __shfl_xor(v0, 1));  v1 = fminf(v1, __shfl_xor(v1, 1));
        if (lid == 0) {
            int row = (r & 3) + 8 * (r >> 2) + 4 * half;
            red[wave * 64 + row]      = v0;
            red[wave * 64 + 32 + row] = v1;
        }
    }
    __syncthreads();
    {
        float v = fmaxf(red[threadIdx.x], 0.0f);
        atomicMin(&minbuf[blockIdx.x * RPB + threadIdx.x], __float_as_uint(v));
    }
#pragma unroll
    for (int s = 0; s < 2; ++s) {
        int c = threadIdx.x + s * 256;
        atomicMin(&minbuf[NPTS + colBase + c], colLds[c]);
    }
}

__global__ __launch_bounds__(1024) void chamfer_reduce_kernel(
    const unsigned int* __restrict__ minbuf, float* __restrict__ out)
{
    __shared__ float red[16];
    const uint4* mb4 = (const uint4*)minbuf;
    float s = 0.0f;
#pragma unroll
    for (int it = 0; it < (2 * NPTS / 4) / 1024; ++it) {
        uint4 u = mb4[it * 1024 + threadIdx.x];
        s += __uint_as_float(u.x) + __uint_as_float(u.y)
           + __uint_as_float(u.z) + __uint_as_float(u.w);
    }
#pragma unroll
    for (int off = 32; off > 0; off >>= 1)
        s += __shfl_down(s, off);
    const int wave = threadIdx.x >> 6;
    const int lane = threadIdx.x & 63;
    if (lane == 0) red[wave] = s;
    __syncthreads();
    if (threadIdx.x == 0) {
        float t = 0.0f;
#pragma unroll
        for (int w = 0; w < 16; ++w) t += red[w];
        out[0] = t * (1.0f / (float)NPTS);
    }
}

extern "C" void kernel_launch(void* const* d_in, const int* in_sizes, int n_in,
                              void* d_out, int out_size, void* d_ws, size_t ws_size,
                              hipStream_t stream) {
    const float4* pred = (const float4*)d_in[0];
    const float4* tgt  = (const float4*)d_in[1];

    char* ws = (char*)d_ws;
    unsigned int* minbuf = (unsigned int*)ws;                      // 128 KB
    uint4* wpred = (uint4*)(ws + (1u << 20));                      // 512 KB
    uint4* ptgt  = wpred + 2 * NPTS;                               // 512 KB
    float* srow  = (float*)(ws + (2u << 20));                      // 8 MB
    float* scol  = (float*)(ws + (10u << 20));                     // 16 MB

    prep_kernel<<<NPTS / 256, 256, 0, stream>>>(pred, tgt, wpred, ptgt, minbuf);

    // ---- measurement probes (4x z-repeat so each lands in rocprof top-5) ----
    dim3 pgrid(NRB, NCB, 4);
    probe_kernel<0><<<pgrid, 256, 0, stream>>>((const bf16x8*)wpred, (const bf16x8*)ptgt, srow, scol);
    probe_kernel<1><<<pgrid, 256, 0, stream>>>((const bf16x8*)wpred, (const bf16x8*)ptgt, srow, scol);
    probe_kernel<2><<<pgrid, 256, 0, stream>>>((const bf16x8*)wpred, (const bf16x8*)ptgt, srow, scol);
    probe_kernel<3><<<pgrid, 256, 0, stream>>>((const bf16x8*)wpred, (const bf16x8*)ptgt, srow, scol);
    probe_kernel<4><<<pgrid, 256, 0, stream>>>((const bf16x8*)wpred, (const bf16x8*)ptgt, srow, scol);

    // ---- real computation (R12 chain) ----
    dim3 grid(NRB, NCB);
    chamfer_mfma_kernel<<<grid, 256, 0, stream>>>(
        (const bf16x8*)wpred, (const bf16x8*)ptgt, minbuf);
    chamfer_reduce_kernel<<<1, 1024, 0, stream>>>(minbuf, (float*)d_out);
}